// Round 3
// baseline (220.034 us; speedup 1.0000x reference)
//
#include <hip/hip_runtime.h>
#include <hip/hip_bf16.h>

// Problem constants (fixed by setup_inputs): B=4, D=32, H=512, W=512, K=16
#define B_ 4
#define D_ 32
#define H_ 512
#define W_ 512
#define K_ 16
#define N_ (H_ * W_)    // 262144 pixels per image
#define NH_ (N_ / 2)    // 131072 float2-pairs per image
#define NBLK_ 512       // attract blocks per image (512 * 256 threads * 2 px = N_)
#define EPAD 33         // sE row pad (bank = (k+d)%32, conflict-free for per-lane k)

// Workspace layout (float indices):
#define WS_SUM  0      // [64]  sum[b][k]   (written by reduce_kernel)
#define WS_CNT  64     // [64]  cnt[b][k]
#define WS_E2   128    // [64]  |E_k|^2
#define WS_LAB  192    // [64]  label at center (int32 reinterpret)
#define WS_E    264    // [2048] E[b][k][d]
#define WS_PART 4096   // [B*NBLK*32] per-block partials: [b][blk][k]=sum, [b][blk][16+k]=cnt

__global__ __launch_bounds__(64) void setup_kernel(
    const float* __restrict__ outp, const int* __restrict__ target,
    const int* __restrict__ centers, float* __restrict__ ws) {
  const int b = blockIdx.x, k = blockIdx.y;
  const int lane = threadIdx.x;
  const int cy = centers[(b * K_ + k) * 2 + 0];
  const int cx = centers[(b * K_ + k) * 2 + 1];
  float v = 0.0f;
  if (lane < D_) {
    v = outp[(((size_t)b * D_ + lane) * H_ + cy) * W_ + cx];
    ws[WS_E + (b * K_ + k) * D_ + lane] = v;
  }
  float s = v * v;
  for (int off = 32; off > 0; off >>= 1) s += __shfl_xor(s, off, 64);
  if (lane == 0) {
    ws[WS_E2 + b * K_ + k] = s;
    ((int*)ws)[WS_LAB + b * K_ + k] = target[(size_t)b * N_ + cy * W_ + cx];
  }
}

__global__ __launch_bounds__(256) void attract_kernel(
    const float* __restrict__ outp, const int* __restrict__ target,
    float* __restrict__ ws) {
  const int b = blockIdx.y;
  const int tid = threadIdx.x;
  __shared__ float sE[K_ * EPAD];
  __shared__ float se2[K_];
  __shared__ int slab[K_];
  __shared__ float bs[K_];   // block hinge sums (LDS float atomics)
  __shared__ float bc[K_];   // block counts

  for (int i = tid; i < K_ * D_; i += 256) {
    const int k = i >> 5, d = i & 31;
    sE[k * EPAD + d] = ws[WS_E + b * (K_ * D_) + i];
  }
  if (tid < K_) {
    se2[tid] = ws[WS_E2 + b * K_ + tid];
    slab[tid] = ((const int*)ws)[WS_LAB + b * K_ + tid];
    bs[tid] = 0.0f;
    bc[tid] = 0.0f;
  }
  __syncthreads();

  // Each thread owns one float2-pair of pixels.
  const int g = blockIdx.x * 256 + tid;            // [0, NH_)
  const float2* xb2 = (const float2*)(outp + (size_t)b * D_ * N_);
  const int2 lab2 = ((const int2*)(target + (size_t)b * N_))[g];

  int kf0 = 0, kf1 = 0, nm0 = 0, nm1 = 0;
#pragma unroll
  for (int k = 0; k < K_; ++k) {
    const int lk = slab[k];
    if (lab2.x == lk) { if (nm0 == 0) kf0 = k; nm0++; }
    if (lab2.y == lk) { if (nm1 == 0) kf1 = k; nm1++; }
  }

  float dot0 = 0.f, dot1 = 0.f, x20 = 0.f, x21 = 0.f;
#pragma unroll 8
  for (int d = 0; d < D_; ++d) {
    const float2 x = xb2[(size_t)d * NH_ + g];
    const float e0 = sE[kf0 * EPAD + d];
    const float e1 = sE[kf1 * EPAD + d];
    dot0 = fmaf(x.x, e0, dot0);
    x20  = fmaf(x.x, x.x, x20);
    dot1 = fmaf(x.y, e1, dot1);
    x21  = fmaf(x.y, x.y, x21);
  }

  if (nm0 > 0) {
    const float d2 = x20 + se2[kf0] - 2.0f * dot0;
    const float h = fmaxf(sqrtf(fmaxf(d2, 0.0f)) - 0.1f, 0.0f);  // DELTA_A=0.1
    atomicAdd(&bs[kf0], h);
    atomicAdd(&bc[kf0], 1.0f);
  }
  if (nm1 > 0) {
    const float d2 = x21 + se2[kf1] - 2.0f * dot1;
    const float h = fmaxf(sqrtf(fmaxf(d2, 0.0f)) - 0.1f, 0.0f);
    atomicAdd(&bs[kf1], h);
    atomicAdd(&bc[kf1], 1.0f);
  }

  // Rare general case: duplicate-label centers (not taken on this input).
  if (__any((nm0 > 1) | (nm1 > 1))) {
    for (int k = 0; k < K_; ++k) {
      const bool need0 = (nm0 > 1) && (lab2.x == slab[k]) && (k != kf0);
      const bool need1 = (nm1 > 1) && (lab2.y == slab[k]) && (k != kf1);
      if (__any(need0 | need1)) {
        float dt0 = 0.f, dt1 = 0.f;
        for (int d = 0; d < D_; ++d) {
          const float2 x = xb2[(size_t)d * NH_ + g];
          const float e = sE[k * EPAD + d];
          dt0 = fmaf(x.x, e, dt0);
          dt1 = fmaf(x.y, e, dt1);
        }
        if (need0) {
          const float d2 = x20 + se2[k] - 2.0f * dt0;
          atomicAdd(&bs[k], fmaxf(sqrtf(fmaxf(d2, 0.0f)) - 0.1f, 0.0f));
          atomicAdd(&bc[k], 1.0f);
        }
        if (need1) {
          const float d2 = x21 + se2[k] - 2.0f * dt1;
          atomicAdd(&bs[k], fmaxf(sqrtf(fmaxf(d2, 0.0f)) - 0.1f, 0.0f));
          atomicAdd(&bc[k], 1.0f);
        }
      }
    }
  }
  __syncthreads();

  // Streamed per-block partials — no global atomics.
  if (tid < 2 * K_) {
    float* p = ws + WS_PART + ((size_t)b * NBLK_ + blockIdx.x) * (2 * K_);
    p[tid] = (tid < K_) ? bs[tid] : bc[tid - K_];
  }
}

__global__ __launch_bounds__(256) void reduce_kernel(const float* __restrict__ ws_in,
                                                     float* __restrict__ ws) {
  // One block per (b, k); sums NBLK_ partials deterministically.
  const int b = blockIdx.x >> 4, k = blockIdx.x & 15;
  const int tid = threadIdx.x;
  const float* base = ws_in + WS_PART + (size_t)b * NBLK_ * (2 * K_);
  float s = 0.0f, c = 0.0f;
  for (int i = tid; i < NBLK_; i += 256) {
    s += base[i * (2 * K_) + k];
    c += base[i * (2 * K_) + K_ + k];
  }
  for (int off = 32; off > 0; off >>= 1) {
    s += __shfl_xor(s, off, 64);
    c += __shfl_xor(c, off, 64);
  }
  __shared__ float rs[4], rc[4];
  if ((tid & 63) == 0) { rs[tid >> 6] = s; rc[tid >> 6] = c; }
  __syncthreads();
  if (tid == 0) {
    ws[WS_SUM + b * K_ + k] = rs[0] + rs[1] + rs[2] + rs[3];
    ws[WS_CNT + b * K_ + k] = rc[0] + rc[1] + rc[2] + rc[3];
  }
}

__global__ __launch_bounds__(256) void final_kernel(const float* __restrict__ ws,
                                                    float* __restrict__ out) {
  __shared__ float sE[B_ * K_ * D_];
  __shared__ float sred[256];
  __shared__ float srep[B_];
  __shared__ float sreg[B_];
  const int tid = threadIdx.x;
  for (int i = tid; i < B_ * K_ * D_; i += 256) sE[i] = ws[WS_E + i];
  __syncthreads();

  const int i = tid >> 4, j = tid & 15;
  for (int b = 0; b < B_; ++b) {
    float dotv = 0.0f;
    for (int d = 0; d < D_; ++d)
      dotv = fmaf(sE[(b * K_ + i) * D_ + d], sE[(b * K_ + j) * D_ + d], dotv);
    const float d2 = ws[WS_E2 + b * K_ + i] + ws[WS_E2 + b * K_ + j] - 2.0f * dotv;
    sred[tid] = fmaxf(1.0f - sqrtf(fmaxf(d2, 0.0f)), 0.0f);  // DELTA_R=1.0
    __syncthreads();
    for (int s = 128; s > 0; s >>= 1) {
      if (tid < s) sred[tid] += sred[tid + s];
      __syncthreads();
    }
    if (tid == 0) srep[b] = sred[0] - (float)K_;
    __syncthreads();
  }

  sred[tid] = (tid < B_ * K_) ? sqrtf(fmaxf(ws[WS_E2 + tid], 0.0f)) : 0.0f;
  __syncthreads();
  if (tid < B_) {
    float s = 0.0f;
    for (int k = 0; k < K_; ++k) s += sred[tid * K_ + k];
    sreg[tid] = s;
  }
  __syncthreads();

  if (tid == 0) {
    float att = 0.0f, rep = 0.0f, reg = 0.0f;
    for (int b = 0; b < B_; ++b) {
      float sa = 0.0f;
      for (int k = 0; k < K_; ++k) {
        const float c = ws[WS_CNT + b * K_ + k];
        sa += ws[WS_SUM + b * K_ + k] / fmaxf(c - 1.0f, 1.0f);
      }
      att = (att + sa) / (float)K_;
      rep = (rep + srep[b]) / (float)(K_ * (K_ - 1));
      reg = (reg + sreg[b]) / (float)K_;
    }
    out[0] = att + rep + 0.001f * reg;  // ALPHA=BETA=1, GAMMA=0.001
    out[1] = att;
    out[2] = rep;
  }
}

extern "C" void kernel_launch(void* const* d_in, const int* in_sizes, int n_in,
                              void* d_out, int out_size, void* d_ws, size_t ws_size,
                              hipStream_t stream) {
  const float* outp = (const float*)d_in[0];
  const int* target = (const int*)d_in[1];
  const int* centers = (const int*)d_in[2];
  float* ws = (float*)d_ws;
  float* out = (float*)d_out;

  setup_kernel<<<dim3(B_, K_), 64, 0, stream>>>(outp, target, centers, ws);
  attract_kernel<<<dim3(NBLK_, B_), 256, 0, stream>>>(outp, target, ws);
  reduce_kernel<<<dim3(B_ * K_), 256, 0, stream>>>(ws, ws);
  final_kernel<<<1, 256, 0, stream>>>(ws, out);
}

// Round 4
// 200.159 us; speedup vs baseline: 1.0993x; 1.0993x over previous
//
#include <hip/hip_runtime.h>
#include <hip/hip_bf16.h>

// Problem constants (fixed by setup_inputs): B=4, D=32, H=512, W=512, K=16
#define B_ 4
#define D_ 32
#define H_ 512
#define W_ 512
#define K_ 16
#define N_ (H_ * W_)    // 262144 pixels per image
#define NQ_ (N_ / 4)    // 65536 float4-quads per image
#define NBLK_ 256       // attract blocks per image (256 blk * 256 thr * 4 px = N_)
#define EPAD 33         // sE row pad: bank=(k*33+d)%32 distinct for distinct k

// Workspace layout (float indices):
#define WS_SUM  0      // [64]  sum[b][k]   (written by reduce_kernel)
#define WS_CNT  64     // [64]  cnt[b][k]
#define WS_E2   128    // [64]  |E_k|^2
#define WS_LAB  192    // [64]  label at center (int32 reinterpret)
#define WS_E    264    // [2048] E[b][k][d]
#define WS_PART 4096   // [B*NBLK*32] per-block partials: [b][blk][k]=sum, [16+k]=cnt

typedef float vfloat4 __attribute__((ext_vector_type(4)));
typedef int vint4 __attribute__((ext_vector_type(4)));

__device__ inline vfloat4 nt_load_f4(const float* p) {
  return __builtin_nontemporal_load((const vfloat4*)p);
}
__device__ inline vint4 nt_load_i4(const int* p) {
  return __builtin_nontemporal_load((const vint4*)p);
}

__global__ __launch_bounds__(64) void setup_kernel(
    const float* __restrict__ outp, const int* __restrict__ target,
    const int* __restrict__ centers, float* __restrict__ ws) {
  const int b = blockIdx.x, k = blockIdx.y;
  const int lane = threadIdx.x;
  const int cy = centers[(b * K_ + k) * 2 + 0];
  const int cx = centers[(b * K_ + k) * 2 + 1];
  float v = 0.0f;
  if (lane < D_) {
    v = outp[(((size_t)b * D_ + lane) * H_ + cy) * W_ + cx];
    ws[WS_E + (b * K_ + k) * D_ + lane] = v;
  }
  float s = v * v;
  for (int off = 32; off > 0; off >>= 1) s += __shfl_xor(s, off, 64);
  if (lane == 0) {
    ws[WS_E2 + b * K_ + k] = s;
    ((int*)ws)[WS_LAB + b * K_ + k] = target[(size_t)b * N_ + cy * W_ + cx];
  }
}

__global__ __launch_bounds__(256) void attract_kernel(
    const float* __restrict__ outp, const int* __restrict__ target,
    float* __restrict__ ws) {
  const int b = blockIdx.y;
  const int tid = threadIdx.x;
  __shared__ float sE[K_ * EPAD];
  __shared__ float se2[K_];
  __shared__ int slab[K_];
  __shared__ float bs[K_];
  __shared__ float bc[K_];

  // Stage E via float4 (d runs in groups of 4 within a k-row; pad between rows).
  if (tid < 128) {
    const vfloat4 v = *(const vfloat4*)(ws + WS_E + b * (K_ * D_) + tid * 4);
    const int k = tid >> 3, d = (tid & 7) * 4;
    sE[k * EPAD + d + 0] = v.x;
    sE[k * EPAD + d + 1] = v.y;
    sE[k * EPAD + d + 2] = v.z;
    sE[k * EPAD + d + 3] = v.w;
  }
  if (tid < K_) {
    se2[tid] = ws[WS_E2 + b * K_ + tid];
    slab[tid] = ((const int*)ws)[WS_LAB + b * K_ + tid];
    bs[tid] = 0.0f;
    bc[tid] = 0.0f;
  }
  __syncthreads();

  // One float4-quad of pixels per thread.
  const int q = blockIdx.x * 256 + tid;  // [0, NQ_)
  const float* xb = outp + (size_t)b * D_ * N_;
  const vint4 lab4 = nt_load_i4(target + (size_t)b * N_ + 4 * q);
  const int labv[4] = {lab4.x, lab4.y, lab4.z, lab4.w};

  int kf[4], nm[4];
#pragma unroll
  for (int j = 0; j < 4; ++j) { kf[j] = 0; nm[j] = 0; }
#pragma unroll
  for (int k = 0; k < K_; ++k) {
    const int lk = slab[k];
#pragma unroll
    for (int j = 0; j < 4; ++j) {
      if (labv[j] == lk) { if (nm[j] == 0) kf[j] = k; nm[j]++; }
    }
  }

  float dot[4] = {0.f, 0.f, 0.f, 0.f};
  float x2[4] = {0.f, 0.f, 0.f, 0.f};
#pragma unroll
  for (int d = 0; d < D_; ++d) {
    const vfloat4 x = nt_load_f4(xb + (size_t)d * N_ + 4 * q);
    const float xs[4] = {x.x, x.y, x.z, x.w};
#pragma unroll
    for (int j = 0; j < 4; ++j) {
      const float e = sE[kf[j] * EPAD + d];
      dot[j] = fmaf(xs[j], e, dot[j]);
      x2[j] = fmaf(xs[j], xs[j], x2[j]);
    }
  }

  float hv[4];
#pragma unroll
  for (int j = 0; j < 4; ++j) {
    const float d2 = x2[j] + se2[kf[j]] - 2.0f * dot[j];
    const float h = fmaxf(sqrtf(fmaxf(d2, 0.0f)) - 0.1f, 0.0f);  // DELTA_A=0.1
    hv[j] = (nm[j] > 0) ? h : 0.0f;
  }
  const bool same = (kf[0] == kf[1]) & (kf[1] == kf[2]) & (kf[2] == kf[3]);
  if (same) {  // common case: lane's 4 consecutive pixels share a label
    const float cs = (float)((nm[0] > 0) + (nm[1] > 0) + (nm[2] > 0) + (nm[3] > 0));
    if (cs > 0.0f) {
      atomicAdd(&bs[kf[0]], hv[0] + hv[1] + hv[2] + hv[3]);
      atomicAdd(&bc[kf[0]], cs);
    }
  } else {
#pragma unroll
    for (int j = 0; j < 4; ++j) {
      if (nm[j] > 0) {
        atomicAdd(&bs[kf[j]], hv[j]);
        atomicAdd(&bc[kf[j]], 1.0f);
      }
    }
  }

  // Rare general case: duplicate-label centers (never taken on this input).
  const bool extra = (nm[0] > 1) | (nm[1] > 1) | (nm[2] > 1) | (nm[3] > 1);
  if (__any(extra)) {
    for (int k = 0; k < K_; ++k) {
      bool need[4]; bool anyn = false;
#pragma unroll
      for (int j = 0; j < 4; ++j) {
        need[j] = (nm[j] > 1) && (labv[j] == slab[k]) && (k != kf[j]);
        anyn |= need[j];
      }
      if (__any(anyn)) {
        float dt[4] = {0.f, 0.f, 0.f, 0.f};
        for (int d = 0; d < D_; ++d) {
          const vfloat4 x = nt_load_f4(xb + (size_t)d * N_ + 4 * q);
          const float e = sE[k * EPAD + d];
          dt[0] = fmaf(x.x, e, dt[0]);
          dt[1] = fmaf(x.y, e, dt[1]);
          dt[2] = fmaf(x.z, e, dt[2]);
          dt[3] = fmaf(x.w, e, dt[3]);
        }
#pragma unroll
        for (int j = 0; j < 4; ++j) {
          if (need[j]) {
            const float d2 = x2[j] + se2[k] - 2.0f * dt[j];
            atomicAdd(&bs[k], fmaxf(sqrtf(fmaxf(d2, 0.0f)) - 0.1f, 0.0f));
            atomicAdd(&bc[k], 1.0f);
          }
        }
      }
    }
  }
  __syncthreads();

  if (tid < 2 * K_) {
    float* p = ws + WS_PART + ((size_t)b * NBLK_ + blockIdx.x) * (2 * K_);
    p[tid] = (tid < K_) ? bs[tid] : bc[tid - K_];
  }
}

__global__ __launch_bounds__(256) void reduce_kernel(const float* __restrict__ ws_in,
                                                     float* __restrict__ ws) {
  // One block per (b, k); sums NBLK_ partials deterministically.
  const int b = blockIdx.x >> 4, k = blockIdx.x & 15;
  const int tid = threadIdx.x;
  const float* base = ws_in + WS_PART + (size_t)b * NBLK_ * (2 * K_);
  float s = 0.0f, c = 0.0f;
  for (int i = tid; i < NBLK_; i += 256) {
    s += base[i * (2 * K_) + k];
    c += base[i * (2 * K_) + K_ + k];
  }
  for (int off = 32; off > 0; off >>= 1) {
    s += __shfl_xor(s, off, 64);
    c += __shfl_xor(c, off, 64);
  }
  __shared__ float rs[4], rc[4];
  if ((tid & 63) == 0) { rs[tid >> 6] = s; rc[tid >> 6] = c; }
  __syncthreads();
  if (tid == 0) {
    ws[WS_SUM + b * K_ + k] = rs[0] + rs[1] + rs[2] + rs[3];
    ws[WS_CNT + b * K_ + k] = rc[0] + rc[1] + rc[2] + rc[3];
  }
}

__global__ __launch_bounds__(256) void final_kernel(const float* __restrict__ ws,
                                                    float* __restrict__ out) {
  __shared__ float sE[B_ * K_ * D_];
  __shared__ float sred[256];
  __shared__ float srep[B_];
  __shared__ float sreg[B_];
  __shared__ float ssa[B_];
  const int tid = threadIdx.x;
  for (int i = tid; i < B_ * K_ * D_; i += 256) sE[i] = ws[WS_E + i];
  __syncthreads();

  // Repulse: 256 pairs per image, tree-reduce per b.
  const int i = tid >> 4, j = tid & 15;
  for (int b = 0; b < B_; ++b) {
    float dotv = 0.0f;
#pragma unroll 8
    for (int d = 0; d < D_; ++d)
      dotv = fmaf(sE[(b * K_ + i) * D_ + d], sE[(b * K_ + j) * D_ + d], dotv);
    const float d2 = ws[WS_E2 + b * K_ + i] + ws[WS_E2 + b * K_ + j] - 2.0f * dotv;
    sred[tid] = fmaxf(1.0f - sqrtf(fmaxf(d2, 0.0f)), 0.0f);  // DELTA_R=1.0
    __syncthreads();
    for (int s = 128; s > 0; s >>= 1) {
      if (tid < s) sred[tid] += sred[tid + s];
      __syncthreads();
    }
    if (tid == 0) srep[b] = sred[0] - (float)K_;
    __syncthreads();
  }

  // Reg: sqrt(|E|^2) summed per b.
  sred[tid] = (tid < B_ * K_) ? sqrtf(fmaxf(ws[WS_E2 + tid], 0.0f)) : 0.0f;
  __syncthreads();
  if (tid < B_) {
    float s = 0.0f;
    for (int k = 0; k < K_; ++k) s += sred[tid * K_ + k];
    sreg[tid] = s;
  }

  // Attract per-b sums: tid<64 = (b,k); butterfly over k bits (16-aligned, safe).
  if (tid < B_ * K_) {
    const float c = ws[WS_CNT + tid];
    float v = ws[WS_SUM + tid] / fmaxf(c - 1.0f, 1.0f);
    for (int off = 1; off < K_; off <<= 1) v += __shfl_xor(v, off, 64);
    if ((tid & 15) == 0) ssa[tid >> 4] = v;
  }
  __syncthreads();

  if (tid == 0) {
    float att = 0.0f, rep = 0.0f, reg = 0.0f;
    for (int b = 0; b < B_; ++b) {
      att = (att + ssa[b]) / (float)K_;
      rep = (rep + srep[b]) / (float)(K_ * (K_ - 1));
      reg = (reg + sreg[b]) / (float)K_;
    }
    out[0] = att + rep + 0.001f * reg;  // ALPHA=BETA=1, GAMMA=0.001
    out[1] = att;
    out[2] = rep;
  }
}

extern "C" void kernel_launch(void* const* d_in, const int* in_sizes, int n_in,
                              void* d_out, int out_size, void* d_ws, size_t ws_size,
                              hipStream_t stream) {
  const float* outp = (const float*)d_in[0];
  const int* target = (const int*)d_in[1];
  const int* centers = (const int*)d_in[2];
  float* ws = (float*)d_ws;
  float* out = (float*)d_out;

  setup_kernel<<<dim3(B_, K_), 64, 0, stream>>>(outp, target, centers, ws);
  attract_kernel<<<dim3(NBLK_, B_), 256, 0, stream>>>(outp, target, ws);
  reduce_kernel<<<dim3(B_ * K_), 256, 0, stream>>>(ws, ws);
  final_kernel<<<1, 256, 0, stream>>>(ws, out);
}